// Round 4
// baseline (76.305 us; speedup 1.0000x reference)
//
#include <hip/hip_runtime.h>

// HexaToParallelogram: out[b, cell] = idx[cell] >= 0 ? hexa[b, idx[cell]] : 0.0f
// B = 32768, NP = 1039, P = 31*39 = 1209.  ~295 MB traffic, fills show ~7.1 TB/s.
//
// R3: wave-local LDS transpose. Per 256-elem tile per wave:
//   phase 1: 4x stride-1 coalesced gathers (1 dword txn/elem) -> LDS
//   phase 2: ds_read_b128 + one global dwordx4 store (0.25 txn/elem)
// No __syncthreads in the loop (same wave produces & consumes; lockstep wave64).
// Index table in LDS, stride-1 reads (2 lanes/bank = free).

constexpr int NP = 1039;
constexpr int P  = 1209;
constexpr int BLOCK = 256;

__global__ void hexa_gather_wave(const float* __restrict__ hexa,
                                 const int* __restrict__ gidx,
                                 float4* __restrict__ out4,
                                 int ntiles) {
  __shared__ int   sidx[P];
  __shared__ float buf[BLOCK / 64][256];

  for (int t = threadIdx.x; t < P; t += BLOCK) sidx[t] = gidx[t];
  __syncthreads();   // once, for sidx only

  const int wid  = threadIdx.x >> 6;
  const int lane = threadIdx.x & 63;
  const int nwaves = gridDim.x * (BLOCK >> 6);

  for (int t = blockIdx.x * (BLOCK >> 6) + wid; t < ntiles; t += nwaves) {
    const int base = t << 8;          // 256 elems per tile

    // ---- phase 1: stride-1 gathers into LDS ----
    int i = base + lane;
    int b = i / P;                    // magic-mul (constant divisor)
    int p = i - b * P;
    int row = b * NP;                 // fits int (max ~34M)
#pragma unroll
    for (int k = 0; k < 4; ++k) {
      int id = sidx[p];
      buf[wid][(k << 6) + lane] = (id >= 0) ? hexa[row + id] : 0.0f;
      p += 64;
      if (p >= P) { p -= P; row += NP; }   // cheap wrap, no divide
    }

    // ---- phase 2: wide store (same wave; compiler inserts lgkmcnt wait) ----
    float4 r = *reinterpret_cast<const float4*>(&buf[wid][lane << 2]);
    out4[(t << 6) + lane] = r;
  }
}

// Fallback: runtime-P scalar path (also covers out_size % 256 != 0).
__global__ void hexa_gather_rt(const float* __restrict__ hexa,
                               const int* __restrict__ gidx,
                               float* __restrict__ out,
                               int n, int Prt) {
  extern __shared__ int sidx[];
  for (int t = threadIdx.x; t < Prt; t += blockDim.x) sidx[t] = gidx[t];
  __syncthreads();
  const int stride = gridDim.x * blockDim.x;
  for (int i = blockIdx.x * blockDim.x + threadIdx.x; i < n; i += stride) {
    int b = i / Prt;
    int p = i - b * Prt;
    int id = sidx[p];
    out[i] = (id >= 0) ? hexa[(size_t)b * NP + id] : 0.0f;
  }
}

extern "C" void kernel_launch(void* const* d_in, const int* in_sizes, int n_in,
                              void* d_out, int out_size, void* d_ws, size_t ws_size,
                              hipStream_t stream) {
  const float* hexa = (const float*)d_in[0];
  const int*   gidx = (const int*)d_in[1];

  if (in_sizes[1] == P && (out_size & 255) == 0) {
    int ntiles = out_size >> 8;
    int grid = (ntiles + (BLOCK >> 6) - 1) / (BLOCK >> 6);
    if (grid > 2048) grid = 2048;     // grid-stride over tiles
    hexa_gather_wave<<<grid, BLOCK, 0, stream>>>(hexa, gidx, (float4*)d_out, ntiles);
  } else {
    int Prt = in_sizes[1];
    int grid = (out_size + BLOCK - 1) / BLOCK;
    if (grid > 2048) grid = 2048;
    hexa_gather_rt<<<grid, BLOCK, (size_t)Prt * sizeof(int), stream>>>(
        hexa, gidx, (float*)d_out, out_size, Prt);
  }
}

// Round 5
// 65.957 us; speedup vs baseline: 1.1569x; 1.1569x over previous
//
#include <hip/hip_runtime.h>

// HexaToParallelogram: out[b, cell] = idx[cell] >= 0 ? hexa[b, idx[cell]] : 0.0f
// B = 32768, NP = 1039, P = 31*39 = 1209. ~295 MB traffic.
//
// R4 model: latency/MLP-bound, not BW-bound (R2/R3 evidence). Structure:
// R1's vec2 ownership (best so far) + 4-way unroll over block-strided chunks:
// each thread carries 8 independent gather loads in flight, phase-split
// (idx reads -> gathers -> stores), branchless via safe-index + select.
// out_size % 2048 == 0 -> no tail in the main kernel.

constexpr int NP = 1039;
constexpr int P  = 1209;
constexpr int BLOCK = 256;
constexpr int UNROLL = 4;           // vec2s per thread per tile

__global__ __launch_bounds__(BLOCK, 8)
void hexa_gather_u4(const float* __restrict__ hexa,
                    const int* __restrict__ gidx,
                    float2* __restrict__ out2,
                    int ntiles) {                 // tile = 1024 vec2s
  __shared__ int sidx[P];
  for (int t = threadIdx.x; t < P; t += BLOCK) sidx[t] = gidx[t];
  __syncthreads();

  for (int tile = blockIdx.x; tile < ntiles; tile += gridDim.x) {
    const int v0 = tile * (BLOCK * UNROLL) + threadIdx.x;

    int   a0[UNROLL], a1[UNROLL];   // flat input offsets (safe)
    int   m0[UNROLL], m1[UNROLL];   // raw ids (sign = mask)
#pragma unroll
    for (int u = 0; u < UNROLL; ++u) {
      int v = v0 + u * BLOCK;
      int i = v * 2;
      int b = i / P;                // magic-mul (constant divisor)
      int p = i - b * P;
      int row = b * NP;             // fits int32 (< 34M)

      int id0 = sidx[p];
      int row1 = row;
      int p1 = p + 1;
      if (p1 == P) { p1 = 0; row1 += NP; }
      int id1 = sidx[p1];

      m0[u] = id0; m1[u] = id1;
      a0[u] = row  + (id0 & ~(id0 >> 31));   // max(id,0): always in-bounds
      a1[u] = row1 + (id1 & ~(id1 >> 31));
    }

    float x0[UNROLL], x1[UNROLL];
#pragma unroll
    for (int u = 0; u < UNROLL; ++u) {       // 8 independent loads in flight
      x0[u] = hexa[a0[u]];
      x1[u] = hexa[a1[u]];
    }

#pragma unroll
    for (int u = 0; u < UNROLL; ++u) {
      float2 r;
      r.x = (m0[u] >= 0) ? x0[u] : 0.0f;
      r.y = (m1[u] >= 0) ? x1[u] : 0.0f;
      out2[v0 + u * BLOCK] = r;
    }
  }
}

// Fallback: runtime-P / non-divisible sizes.
__global__ void hexa_gather_rt(const float* __restrict__ hexa,
                               const int* __restrict__ gidx,
                               float* __restrict__ out,
                               int n, int Prt) {
  extern __shared__ int sidx[];
  for (int t = threadIdx.x; t < Prt; t += blockDim.x) sidx[t] = gidx[t];
  __syncthreads();
  const int stride = gridDim.x * blockDim.x;
  for (int i = blockIdx.x * blockDim.x + threadIdx.x; i < n; i += stride) {
    int b = i / Prt;
    int p = i - b * Prt;
    int id = sidx[p];
    out[i] = (id >= 0) ? hexa[(size_t)b * NP + id] : 0.0f;
  }
}

extern "C" void kernel_launch(void* const* d_in, const int* in_sizes, int n_in,
                              void* d_out, int out_size, void* d_ws, size_t ws_size,
                              hipStream_t stream) {
  const float* hexa = (const float*)d_in[0];
  const int*   gidx = (const int*)d_in[1];

  const int tile_elems = BLOCK * UNROLL * 2;   // 2048
  if (in_sizes[1] == P && out_size % tile_elems == 0) {
    int ntiles = out_size / tile_elems;
    int grid = ntiles < 2048 ? ntiles : 2048;
    hexa_gather_u4<<<grid, BLOCK, 0, stream>>>(hexa, gidx, (float2*)d_out, ntiles);
  } else {
    int Prt = in_sizes[1];
    int grid = (out_size + BLOCK - 1) / BLOCK;
    if (grid > 2048) grid = 2048;
    hexa_gather_rt<<<grid, BLOCK, (size_t)Prt * sizeof(int), stream>>>(
        hexa, gidx, (float*)d_out, out_size, Prt);
  }
}

// Round 6
// 51.671 us; speedup vs baseline: 1.4767x; 1.2765x over previous
//
#include <hip/hip_runtime.h>

// HexaToParallelogram: out[b, cell] = idx[cell] >= 0 ? hexa[b, idx[cell]] : 0.0f
// B = 32768, NP = 1039, P = 31*39 = 1209. ~295 MB round-trip traffic.
//
// R5 theory: input (136 MB) fits the 256 MiB L3, but input+output doesn't.
// Non-temporal stores keep the write stream from evicting the input, so
// graph replays read the input from L3 instead of HBM.
// Structure: R1's vec2 ownership (best measured) + UNROLL=2 for 4 independent
// gathers in flight, NO launch_bounds cap (R4's 64-VGPR cap caused the
// regression), branchless masking.

constexpr int NP = 1039;
constexpr int P  = 1209;
constexpr int BLOCK = 256;
constexpr int UNROLL = 2;           // vec2s per thread per tile

typedef float f32x2 __attribute__((ext_vector_type(2)));

__global__ void hexa_gather_nt(const float* __restrict__ hexa,
                               const int* __restrict__ gidx,
                               f32x2* __restrict__ out2,
                               int ntiles) {            // tile = BLOCK*UNROLL vec2s
  __shared__ int sidx[P];
  for (int t = threadIdx.x; t < P; t += BLOCK) sidx[t] = gidx[t];
  __syncthreads();

  for (int tile = blockIdx.x; tile < ntiles; tile += gridDim.x) {
    const int v0 = tile * (BLOCK * UNROLL) + threadIdx.x;

    f32x2 r[UNROLL];
#pragma unroll
    for (int u = 0; u < UNROLL; ++u) {
      int v = v0 + u * BLOCK;
      int i = v * 2;
      int b = i / P;                // magic-mul (constant divisor)
      int p = i - b * P;
      int row = b * NP;             // fits int32 (< 34M)

      int id0 = sidx[p];
      int p1 = p + 1, row1 = row;
      if (p1 == P) { p1 = 0; row1 += NP; }
      int id1 = sidx[p1];

      // branchless: always load a safe address, select after
      float x0 = hexa[row  + (id0 & ~(id0 >> 31))];
      float x1 = hexa[row1 + (id1 & ~(id1 >> 31))];
      r[u].x = (id0 >= 0) ? x0 : 0.0f;
      r[u].y = (id1 >= 0) ? x1 : 0.0f;
    }

#pragma unroll
    for (int u = 0; u < UNROLL; ++u)
      __builtin_nontemporal_store(r[u], &out2[v0 + u * BLOCK]);
  }
}

// Fallback: runtime-P / non-divisible sizes.
__global__ void hexa_gather_rt(const float* __restrict__ hexa,
                               const int* __restrict__ gidx,
                               float* __restrict__ out,
                               int n, int Prt) {
  extern __shared__ int sidx[];
  for (int t = threadIdx.x; t < Prt; t += blockDim.x) sidx[t] = gidx[t];
  __syncthreads();
  const int stride = gridDim.x * blockDim.x;
  for (int i = blockIdx.x * blockDim.x + threadIdx.x; i < n; i += stride) {
    int b = i / Prt;
    int p = i - b * Prt;
    int id = sidx[p];
    out[i] = (id >= 0) ? hexa[(size_t)b * NP + id] : 0.0f;
  }
}

extern "C" void kernel_launch(void* const* d_in, const int* in_sizes, int n_in,
                              void* d_out, int out_size, void* d_ws, size_t ws_size,
                              hipStream_t stream) {
  const float* hexa = (const float*)d_in[0];
  const int*   gidx = (const int*)d_in[1];

  const int tile_elems = BLOCK * UNROLL * 2;   // 1024
  if (in_sizes[1] == P && out_size % tile_elems == 0) {
    int ntiles = out_size / tile_elems;        // 38688
    int grid = ntiles < 2048 ? ntiles : 2048;
    hexa_gather_nt<<<grid, BLOCK, 0, stream>>>(hexa, gidx, (f32x2*)d_out, ntiles);
  } else {
    int Prt = in_sizes[1];
    int grid = (out_size + BLOCK - 1) / BLOCK;
    if (grid > 2048) grid = 2048;
    hexa_gather_rt<<<grid, BLOCK, (size_t)Prt * sizeof(int), stream>>>(
        hexa, gidx, (float*)d_out, out_size, Prt);
  }
}

// Round 7
// 50.557 us; speedup vs baseline: 1.5093x; 1.0220x over previous
//
#include <hip/hip_runtime.h>

// HexaToParallelogram: out[b, cell] = idx[cell] >= 0 ? hexa[b, idx[cell]] : 0.0f
// B = 32768, NP = 1039, P = 31*39 = 1209. ~295 MB round-trip traffic.
//
// R6: R5 structure (vec2 ownership, sidx in LDS, branchless gather,
// non-temporal stores) with UNROLL 2->4 (8 gathers in flight/thread, no
// launch_bounds cap -- R4's 64-VGPR cap was its regression) and the
// magic-divide hoisted out of the unroll body (chunk stride 512 < P, so a
// single conditional wrap replaces the per-u divide).

constexpr int NP = 1039;
constexpr int P  = 1209;
constexpr int BLOCK = 256;
constexpr int UNROLL = 4;           // vec2s per thread per tile

typedef float f32x2 __attribute__((ext_vector_type(2)));

__global__ void hexa_gather_nt4(const float* __restrict__ hexa,
                                const int* __restrict__ gidx,
                                f32x2* __restrict__ out2,
                                int ntiles) {           // tile = BLOCK*UNROLL vec2s
  __shared__ int sidx[P];
  for (int t = threadIdx.x; t < P; t += BLOCK) sidx[t] = gidx[t];
  __syncthreads();

  for (int tile = blockIdx.x; tile < ntiles; tile += gridDim.x) {
    const int v0 = tile * (BLOCK * UNROLL) + threadIdx.x;

    // address generation: one magic-divide, then incremental wrap (+512 < P)
    int i0 = v0 * 2;
    int b  = i0 / P;
    int p  = i0 - b * P;
    int row = b * NP;               // fits int32 (< 34M)

    int   m0[UNROLL], m1[UNROLL];
    float x0[UNROLL], x1[UNROLL];
#pragma unroll
    for (int u = 0; u < UNROLL; ++u) {
      int id0 = sidx[p];
      int p1 = p + 1, row1 = row;
      if (p1 == P) { p1 = 0; row1 += NP; }
      int id1 = sidx[p1];

      m0[u] = id0; m1[u] = id1;
      x0[u] = hexa[row  + (id0 & ~(id0 >> 31))];   // branchless safe gather
      x1[u] = hexa[row1 + (id1 & ~(id1 >> 31))];

      p += 2 * BLOCK;               // advance 512 elements
      if (p >= P) { p -= P; row += NP; }
    }

#pragma unroll
    for (int u = 0; u < UNROLL; ++u) {
      f32x2 r;
      r.x = (m0[u] >= 0) ? x0[u] : 0.0f;
      r.y = (m1[u] >= 0) ? x1[u] : 0.0f;
      __builtin_nontemporal_store(r, &out2[v0 + u * BLOCK]);
    }
  }
}

// Fallback: runtime-P / non-divisible sizes.
__global__ void hexa_gather_rt(const float* __restrict__ hexa,
                               const int* __restrict__ gidx,
                               float* __restrict__ out,
                               int n, int Prt) {
  extern __shared__ int sidx[];
  for (int t = threadIdx.x; t < Prt; t += blockDim.x) sidx[t] = gidx[t];
  __syncthreads();
  const int stride = gridDim.x * blockDim.x;
  for (int i = blockIdx.x * blockDim.x + threadIdx.x; i < n; i += stride) {
    int b = i / Prt;
    int p = i - b * Prt;
    int id = sidx[p];
    out[i] = (id >= 0) ? hexa[(size_t)b * NP + id] : 0.0f;
  }
}

extern "C" void kernel_launch(void* const* d_in, const int* in_sizes, int n_in,
                              void* d_out, int out_size, void* d_ws, size_t ws_size,
                              hipStream_t stream) {
  const float* hexa = (const float*)d_in[0];
  const int*   gidx = (const int*)d_in[1];

  const int tile_elems = BLOCK * UNROLL * 2;   // 2048
  if (in_sizes[1] == P && out_size % tile_elems == 0) {
    int ntiles = out_size / tile_elems;        // 19344
    int grid = ntiles < 2048 ? ntiles : 2048;
    hexa_gather_nt4<<<grid, BLOCK, 0, stream>>>(hexa, gidx, (f32x2*)d_out, ntiles);
  } else {
    int Prt = in_sizes[1];
    int grid = (out_size + BLOCK - 1) / BLOCK;
    if (grid > 2048) grid = 2048;
    hexa_gather_rt<<<grid, BLOCK, (size_t)Prt * sizeof(int), stream>>>(
        hexa, gidx, (float*)d_out, out_size, Prt);
  }
}